// Round 5
// baseline (156.222 us; speedup 1.0000x reference)
//
#include <hip/hip_runtime.h>
#include <hip/hip_bf16.h>

// Problem constants (from reference)
#define V 50000
#define D 128
#define B 2048
#define P 20

// Stage-1: x[B][D] = inputs[B][V] @ W_emb[D][V]^T, split-K
#define BM 256                  // 8 m-tiles
#define NSPLIT 64               // KC=784: 63 full splits + tail 608
#define KC 784
#define NMT (B / BM)            // 8

typedef float  f32x4   __attribute__((ext_vector_type(4)));
typedef short  bf16x8  __attribute__((ext_vector_type(8)));
typedef unsigned int uint4v __attribute__((ext_vector_type(4)));

// truncating fp32->bf16 pack of two floats into one u32 (low = a, high = b)
__device__ __forceinline__ unsigned int pk2(float a, float b) {
    return (__float_as_uint(b) & 0xFFFF0000u) | (__float_as_uint(a) >> 16);
}
// RNE fp32->bf16
__device__ __forceinline__ unsigned short f2bf(float f) {
    unsigned int u = __float_as_uint(f);
    return (unsigned short)((u + 0x7FFFu + ((u >> 16) & 1u)) >> 16);
}
__device__ __forceinline__ bf16x8 pack8(f32x4 lo, f32x4 hi) {
    union { uint4v u; bf16x8 h; } r;
    r.u.x = pk2(lo[0], lo[1]); r.u.y = pk2(lo[2], lo[3]);
    r.u.z = pk2(hi[0], hi[1]); r.u.w = pk2(hi[2], hi[3]);
    return r.h;
}
// async global->LDS, 16 B per lane; LDS dest is wave-uniform base + lane*16
__device__ __forceinline__ void gload_lds16(const void* g, void* l) {
    __builtin_amdgcn_global_load_lds(
        (const __attribute__((address_space(1))) unsigned int*)g,
        (__attribute__((address_space(3))) unsigned int*)l, 16, 0, 0);
}

// ---------------- pre-pass: W_emb fp32 -> bf16 (same [D][V] layout) ----------------
__global__ __launch_bounds__(256)
void w2v_wcast(const float* __restrict__ Wemb, unsigned* __restrict__ Wb) {
    const size_t t = (size_t)blockIdx.x * 256 + threadIdx.x;   // 8 elems/thread
    const size_t base = t * 8;
    if (base >= (size_t)D * V) return;
    const f32x4* src = reinterpret_cast<const f32x4*>(Wemb + base);
    f32x4 v0 = src[0], v1 = src[1];
    uint4v u;
    u.x = pk2(v0[0], v0[1]); u.y = pk2(v0[2], v0[3]);
    u.z = pk2(v1[0], v1[1]); u.w = pk2(v1[2], v1[3]);
    *reinterpret_cast<uint4v*>(Wb + base / 2) = u;
}

// ---------------- stage 1: split-K GEMM ----------------
// FAST=1: W bf16 staged via global_load_lds, double-buffered, 1 barrier/k-step.
// FAST=0: fallback, W fp32 staged via VGPRs each step, atomic fp32 output.
template<int FAST>
__global__ __launch_bounds__(512, 4)
void w2v_gemm(const float* __restrict__ Ain, const void* __restrict__ Wsrc,
              void* __restrict__ part, int use_atomic) {
    // [0,16K)=W buf0, [16K,32K)=W buf1; epilogue reuses all 64 KB as C tile
    __shared__ uint4v smem4[4096];
    char* smem = (char*)smem4;

    // XCD-aware mapping: the 8 m-blocks of a split share one XCD
    const int i   = blockIdx.x;            // 0..511
    const int xcd = i & 7;
    const int j   = i >> 3;                // 0..63
    const int s   = xcd * 8 + (j >> 3);    // 0..63
    const int mt  = j & 7;
    const int m0  = mt * BM;
    const int k0  = s * KC;
    const int k1  = (k0 + KC < V) ? (k0 + KC) : V;
    const int nfull = (k1 - k0) >> 6;      // 12 (last split: 9)
    const int ktail = (k1 - k0) & 63;      // 16 (last split: 32)

    const int tid  = threadIdx.x;
    const int lane = tid & 63;
    const int wid  = tid >> 6;             // 0..7 -> rows [wid*32, wid*32+32)
    const int fr   = lane & 15;
    const int kg4  = lane >> 4;            // 0..3

    f32x4 acc[2][8] = {};

    const float* Arow0 = Ain + (size_t)(m0 + wid * 32 + fr) * V;   // m-frag 0
    const float* Arow1 = Arow0 + (size_t)16 * V;                   // m-frag 1

    const unsigned short* Wb = (const unsigned short*)Wsrc;        // FAST
    const float*          Wf = (const float*)Wsrc;                 // !FAST

    // FAST staging: wave wid stages rows [wid*16, wid*16+16), 2 calls x 1 KB.
    // Linear LDS dest; source k-group pre-swizzled: c8_src = (l&7) ^ (d&7).
    const int drow = wid * 16 + (lane >> 3);      // call-0 row; call-1 row = +8 (same d&7)
    const int c8s  = (lane & 7) ^ (drow & 7);
    const unsigned short* gW0 = Wb + (size_t)drow * V + 8 * c8s;
    const unsigned short* gW1 = gW0 + (size_t)8 * V;
    char* lW = smem + (size_t)(wid * 16) * 128;   // +buf*16384; call-1 at +1024

    // guarded VGPR staging (tail / fallback): linear-dst slot c8l, source c8l^(d&7)
    auto stage_guard = [&](int buf, int ks) {
#pragma unroll
        for (int t2 = 0; t2 < 2; ++t2) {
            const int slot = tid + t2 * 512;      // 1024 slots x 16 B
            const int d    = slot >> 3;
            const int c8l  = slot & 7;
            const int c8   = c8l ^ (d & 7);
            const int kg   = ks + c8 * 8;
            uint4v u = {0u, 0u, 0u, 0u};
            if (kg < k1) {
                if (FAST) {
                    u = *reinterpret_cast<const uint4v*>(Wb + (size_t)d * V + kg);
                } else {
                    const f32x4* sp = reinterpret_cast<const f32x4*>(Wf + (size_t)d * V + kg);
                    f32x4 v0 = sp[0], v1 = sp[1];
                    u.x = pk2(v0[0], v0[1]); u.y = pk2(v0[2], v0[3]);
                    u.z = pk2(v1[0], v1[1]); u.w = pk2(v1[2], v1[3]);
                }
            }
            *reinterpret_cast<uint4v*>(smem + buf * 16384 + d * 128 + c8l * 16) = u;
        }
    };

    int buf = 0;
    if (FAST) {
        // prologue: stage step-0 W into buf0
        gload_lds16(gW0 + k0, lW);
        gload_lds16(gW1 + k0, lW + 1024);
        __syncthreads();
        for (int t = 0; t < nfull; ++t) {
            const int ks   = k0 + t * 64;
            const int koff = ks + kg4 * 8;
            // A loads first (the critical stream; 8 independent dwordx4)
            const f32x4* p0 = reinterpret_cast<const f32x4*>(Arow0 + koff);
            const f32x4* p1 = reinterpret_cast<const f32x4*>(Arow1 + koff);
            const f32x4 a00l = p0[0], a00h = p0[1];
            const f32x4 a01l = p1[0], a01h = p1[1];
            const f32x4 a10l = p0[8], a10h = p0[9];   // koff+32
            const f32x4 a11l = p1[8], a11h = p1[9];
            // prefetch next W tile (async, drained only at the barrier)
            if (t + 1 < nfull) {
                char* nb = smem + (buf ^ 1) * 16384 + (size_t)(wid * 16) * 128;
                gload_lds16(gW0 + (ks + 64), nb);
                gload_lds16(gW1 + (ks + 64), nb + 1024);
            }
            const bf16x8 af00 = pack8(a00l, a00h), af01 = pack8(a01l, a01h);
            const bf16x8 af10 = pack8(a10l, a10h), af11 = pack8(a11l, a11h);
            char* wb = smem + buf * 16384;
            const unsigned kb0 = (unsigned)kg4 << 4;
#pragma unroll
            for (int n = 0; n < 8; ++n) {
                const int r = n * 16 + fr;
                const unsigned sw = (unsigned)(r & 7) << 4;
                const char* rp = wb + r * 128;
                const bf16x8 wf0 = *reinterpret_cast<const bf16x8*>(rp + (kb0 ^ sw));
                const bf16x8 wf1 = *reinterpret_cast<const bf16x8*>(rp + ((kb0 + 64u) ^ sw));
                acc[0][n] = __builtin_amdgcn_mfma_f32_16x16x32_bf16(af00, wf0, acc[0][n], 0, 0, 0);
                acc[1][n] = __builtin_amdgcn_mfma_f32_16x16x32_bf16(af01, wf0, acc[1][n], 0, 0, 0);
                acc[0][n] = __builtin_amdgcn_mfma_f32_16x16x32_bf16(af10, wf1, acc[0][n], 0, 0, 0);
                acc[1][n] = __builtin_amdgcn_mfma_f32_16x16x32_bf16(af11, wf1, acc[1][n], 0, 0, 0);
            }
            __syncthreads();
            buf ^= 1;
        }
        if (ktail) {                        // 16 or 32 k; W zero-padded, A x 0 harmless
            const int ks = k0 + nfull * 64;
            stage_guard(buf, ks);
            __syncthreads();
            const int koff = ks + kg4 * 8;
            const f32x4* p0 = reinterpret_cast<const f32x4*>(Arow0 + koff);
            const f32x4* p1 = reinterpret_cast<const f32x4*>(Arow1 + koff);
            const bf16x8 af00 = pack8(p0[0], p0[1]);
            const bf16x8 af01 = pack8(p1[0], p1[1]);
            char* wb = smem + buf * 16384;
            const unsigned kb0 = (unsigned)kg4 << 4;
#pragma unroll
            for (int n = 0; n < 8; ++n) {
                const int r = n * 16 + fr;
                const unsigned sw = (unsigned)(r & 7) << 4;
                const bf16x8 wf0 = *reinterpret_cast<const bf16x8*>(wb + r * 128 + (kb0 ^ sw));
                acc[0][n] = __builtin_amdgcn_mfma_f32_16x16x32_bf16(af00, wf0, acc[0][n], 0, 0, 0);
                acc[1][n] = __builtin_amdgcn_mfma_f32_16x16x32_bf16(af01, wf0, acc[1][n], 0, 0, 0);
            }
            __syncthreads();
        }
    } else {
        for (int ks = k0; ks < k1; ks += 64) {
            stage_guard(0, ks);
            __syncthreads();
            const int koff = ks + kg4 * 8;
            const f32x4* p0 = reinterpret_cast<const f32x4*>(Arow0 + koff);
            const f32x4* p1 = reinterpret_cast<const f32x4*>(Arow1 + koff);
            const bf16x8 af00 = pack8(p0[0], p0[1]);
            const bf16x8 af01 = pack8(p1[0], p1[1]);
            const bool kh1v = (ks + 32 < k1);
            bf16x8 af10 = {}, af11 = {};
            if (kh1v) { af10 = pack8(p0[8], p0[9]); af11 = pack8(p1[8], p1[9]); }
            const unsigned kb0 = (unsigned)kg4 << 4;
#pragma unroll
            for (int n = 0; n < 8; ++n) {
                const int r = n * 16 + fr;
                const unsigned sw = (unsigned)(r & 7) << 4;
                const char* rp = smem + r * 128;
                const bf16x8 wf0 = *reinterpret_cast<const bf16x8*>(rp + (kb0 ^ sw));
                acc[0][n] = __builtin_amdgcn_mfma_f32_16x16x32_bf16(af00, wf0, acc[0][n], 0, 0, 0);
                acc[1][n] = __builtin_amdgcn_mfma_f32_16x16x32_bf16(af01, wf0, acc[1][n], 0, 0, 0);
                if (kh1v) {
                    const bf16x8 wf1 = *reinterpret_cast<const bf16x8*>(rp + ((kb0 + 64u) ^ sw));
                    acc[0][n] = __builtin_amdgcn_mfma_f32_16x16x32_bf16(af10, wf1, acc[0][n], 0, 0, 0);
                    acc[1][n] = __builtin_amdgcn_mfma_f32_16x16x32_bf16(af11, wf1, acc[1][n], 0, 0, 0);
                }
            }
            __syncthreads();
        }
    }

    // ---- epilogue ----
    if (use_atomic) {
        float* outp = (float*)part;        // fp32 [B][D]
#pragma unroll
        for (int m = 0; m < 2; ++m) {
            const int r0 = m0 + wid * 32 + m * 16 + kg4 * 4;
#pragma unroll
            for (int n = 0; n < 8; ++n) {
                const int c0 = n * 16 + fr;
#pragma unroll
                for (int jj = 0; jj < 4; ++jj)
                    atomicAdd(&outp[(size_t)(r0 + jj) * D + c0], acc[m][n][jj]);
            }
        }
        return;
    }
    // bf16 C tile via LDS (smem free after last barrier), then 16B/lane stream-out
    unsigned short* Cs = (unsigned short*)smem;   // [256][128]
#pragma unroll
    for (int m = 0; m < 2; ++m) {
        const int r0 = wid * 32 + m * 16 + kg4 * 4;
#pragma unroll
        for (int n = 0; n < 8; ++n) {
            const int c0 = n * 16 + fr;
#pragma unroll
            for (int jj = 0; jj < 4; ++jj)
                Cs[(r0 + jj) * 128 + c0] = f2bf(acc[m][n][jj]);
        }
    }
    __syncthreads();
    char* dstb = (char*)part + ((size_t)s * B + m0) * (D * 2);   // [s][b][d] bf16
#pragma unroll
    for (int it = 0; it < 8; ++it) {
        const int off = (it * 512 + tid) * 16;                   // 0..65535
        uint4v v = *reinterpret_cast<const uint4v*>(smem + off);
        *reinterpret_cast<uint4v*>(dstb + off) = v;
    }
}

// ---------------- stage 2: reduce splits + gathered cls dots + BCE + mean ----------------
__global__ __launch_bounds__(256)
void w2v_loss(const void* __restrict__ part, int nsplit, int part_bf16,
              const float* __restrict__ Wcls, const int* __restrict__ pathIdx,
              const float* __restrict__ codes, const float* __restrict__ mask,
              float* __restrict__ out) {
    const int lane = threadIdx.x & 63;
    const int wid  = threadIdx.x >> 6;
    const int b    = blockIdx.x * 4 + wid;     // one wave per sample

    float x0 = 0.f, x1 = 0.f;                  // x[b][2*lane], x[b][2*lane+1]
    if (part_bf16) {
        const unsigned* pb = (const unsigned*)part;   // 64 u32 per [s][b] row
        for (int s = 0; s < nsplit; ++s) {
            unsigned u = pb[((size_t)s * B + b) * 64 + lane];
            x0 += __uint_as_float(u << 16);
            x1 += __uint_as_float(u & 0xFFFF0000u);
        }
    } else {
        const float* pf = (const float*)part;         // [B][D] fp32, pre-reduced
        const float2 v = *reinterpret_cast<const float2*>(&pf[(size_t)b * D + lane * 2]);
        x0 = v.x; x1 = v.y;
    }

    float lsum = 0.f, msum = 0.f;
#pragma unroll
    for (int p = 0; p < P; ++p) {
        int node = pathIdx[b * P + p];
        const float2 w = *reinterpret_cast<const float2*>(&Wcls[(size_t)node * D + lane * 2]);
        float d = x0 * w.x + x1 * w.y;
#pragma unroll
        for (int off = 1; off < 64; off <<= 1)
            d += __shfl_xor(d, off, 64);
        float t  = codes[b * P + p];
        float mm = mask[b * P + p];
        float loss = fmaxf(d, 0.f) - d * t + log1pf(__expf(-fabsf(d)));
        lsum += loss * mm;
        msum += mm;
    }
    float per = (msum > 0.f) ? (lsum / msum) : 0.f;

    __shared__ float wsum[4];
    if (lane == 0) wsum[wid] = per;
    __syncthreads();
    if (threadIdx.x == 0) {
        float ssum = wsum[0] + wsum[1] + wsum[2] + wsum[3];
        atomicAdd(out, ssum * (1.0f / (float)B));
    }
}

extern "C" void kernel_launch(void* const* d_in, const int* in_sizes, int n_in,
                              void* d_out, int out_size, void* d_ws, size_t ws_size,
                              hipStream_t stream) {
    const float* inputs = (const float*)d_in[0];   // [B,V]
    const float* W_emb  = (const float*)d_in[1];   // [D,V]
    const float* W_cls  = (const float*)d_in[2];   // [V,D]
    const int*   path   = (const int*)  d_in[3];   // [B,P]
    const float* codes  = (const float*)d_in[4];   // [B,P]
    const float* mask   = (const float*)d_in[5];   // [B,P]
    float* out = (float*)d_out;

    hipMemsetAsync(d_out, 0, sizeof(float), stream);

    const size_t wb_bytes  = (size_t)D * V * 2;                       // 12.8 MB bf16 W
    const size_t part_off  = (wb_bytes + 255) & ~(size_t)255;
    const size_t part_need = part_off + (size_t)NSPLIT * B * D * 2;   // ~46 MB

    if (ws_size >= part_need) {
        unsigned* Wb  = (unsigned*)d_ws;
        char* partp   = (char*)d_ws + part_off;
        w2v_wcast<<<dim3((D * V / 8 + 255) / 256), dim3(256), 0, stream>>>(W_emb, Wb);
        w2v_gemm<1><<<dim3(NMT * NSPLIT), dim3(512), 0, stream>>>(inputs, Wb, partp, 0);
        w2v_loss<<<dim3(B / 4), dim3(256), 0, stream>>>(partp, NSPLIT, 1,
                                                        W_cls, path, codes, mask, out);
    } else {
        hipMemsetAsync(d_ws, 0, (size_t)B * D * sizeof(float), stream);
        w2v_gemm<0><<<dim3(NMT * NSPLIT), dim3(512), 0, stream>>>(inputs, W_emb, d_ws, 1);
        w2v_loss<<<dim3(B / 4), dim3(256), 0, stream>>>(d_ws, 1, 0,
                                                        W_cls, path, codes, mask, out);
    }
}

// Round 6
// 144.967 us; speedup vs baseline: 1.0776x; 1.0776x over previous
//
#include <hip/hip_runtime.h>
#include <hip/hip_bf16.h>

// Problem constants (from reference)
#define V 50000
#define D 128
#define B 2048
#define P 20

// Stage-1: x[B][D] = inputs[B][V] @ W_emb[D][V]^T, split-K
#define BM 128
#define BK 32
#define NSPLIT 48               // 8 XCDs x 6 splits; grid 16*48=768 = exactly 3 blocks/CU
#define KC 1056                 // 33 full 32-k steps; split 47: 368 k = 11 steps + 16 tail
#define VPAD (NSPLIT * KC)      // 50688 (zero-padded bf16 W)
#define NMT (B / BM)            // 16

typedef float  f32x4  __attribute__((ext_vector_type(4)));
typedef short  bf16x8 __attribute__((ext_vector_type(8)));
typedef unsigned int uint4v __attribute__((ext_vector_type(4)));

// truncating fp32->bf16 pack of two floats into one u32 (low = a, high = b)
__device__ __forceinline__ unsigned int pk2(float a, float b) {
    return (__float_as_uint(b) & 0xFFFF0000u) | (__float_as_uint(a) >> 16);
}
// RNE fp32->bf16
__device__ __forceinline__ unsigned short f2bf(float f) {
    unsigned int u = __float_as_uint(f);
    return (unsigned short)((u + 0x7FFFu + ((u >> 16) & 1u)) >> 16);
}
__device__ __forceinline__ bf16x8 pack8(f32x4 lo, f32x4 hi) {
    union { uint4v u; bf16x8 h; } r;
    r.u.x = pk2(lo[0], lo[1]); r.u.y = pk2(lo[2], lo[3]);
    r.u.z = pk2(hi[0], hi[1]); r.u.w = pk2(hi[2], hi[3]);
    return r.h;
}
// async global->LDS, 16 B per lane; LDS dest = wave-uniform base + lane*16
__device__ __forceinline__ void gload_lds16(const void* g, void* l) {
    __builtin_amdgcn_global_load_lds(
        (const __attribute__((address_space(1))) unsigned int*)g,
        (__attribute__((address_space(3))) unsigned int*)l, 16, 0, 0);
}

// ---------------- pre-pass: W_emb fp32 [D][V] -> bf16 [D][VPAD], zero pad ----------------
__global__ __launch_bounds__(256)
void w2v_wcast(const float* __restrict__ Wemb, unsigned short* __restrict__ Wb) {
    const size_t t = (size_t)blockIdx.x * 256 + threadIdx.x;
    const size_t n = (size_t)D * VPAD / 8;       // 811008 -> grid 3168 exact
    if (t >= n) return;
    const size_t base = t * 8;                   // padded coords, 8-aligned
    const int d = (int)(base / VPAD);
    const int k = (int)(base % VPAD);            // VPAD%8==0 -> k%8==0
    uint4v u = {0u, 0u, 0u, 0u};
    if (k + 8 <= V) {                            // V%8==0 -> chunks fully valid or fully pad
        const f32x4* src = reinterpret_cast<const f32x4*>(Wemb + (size_t)d * V + k);
        f32x4 v0 = src[0], v1 = src[1];
        u.x = pk2(v0[0], v0[1]); u.y = pk2(v0[2], v0[3]);
        u.z = pk2(v1[0], v1[1]); u.w = pk2(v1[2], v1[3]);
    }
    *reinterpret_cast<uint4v*>(Wb + (size_t)d * VPAD + k) = u;
}

// ---------------- stage 1: split-K GEMM, ALL global traffic via async global->LDS ----------------
// LDS: A bufs (fp32, XOR-swizzled chunks) at 0/16384; W bufs (bf16) at 32768/40960. 48 KB.
// 2-phase: STAGE(t+1) -> compute(t) -> __syncthreads (its vmcnt(0)+barrier IS the phase drain).
template<int FAST>
__global__ __launch_bounds__(256, 3)
void w2v_gemm(const float* __restrict__ Ain, const void* __restrict__ Wsrc,
              void* __restrict__ part) {
    __shared__ char smem[49152];

    // XCD-aware mapping: the 16 m-blocks of a split share one XCD
    const int i   = blockIdx.x;            // 0..767
    const int xcd = i & 7;
    const int q   = i >> 3;                // 0..95
    const int s   = xcd * 6 + (q >> 4);    // 0..47
    const int mt  = q & 15;
    const int m0  = mt * BM;
    const int k0  = s * KC;
    const int k1  = (k0 + KC < V) ? (k0 + KC) : V;
    const int nfull  = (k1 - k0) >> 5;
    const int ktail  = (k1 - k0) & 31;     // 0 except split 47 (16)
    const int nsteps = nfull + (ktail ? 1 : 0);

    const int tid  = threadIdx.x;
    const int lane = tid & 63;
    const int wid  = tid >> 6;
    const int w32  = wid * 32;             // wave owns rows [w32, w32+32)
    const int fr   = lane & 15;
    const int kg4  = lane >> 4;

    f32x4 acc[2][8] = {};

    // A staging source (per-lane): row w32 + j*8 + (l>>3); chunk swizzle (l&7)^(l>>3)
    const int arow = w32 + (lane >> 3);
    const int csrc = (lane & 7) ^ (lane >> 3);
    const float* aSrc = Ain + (size_t)(m0 + arow) * V + csrc * 4;

    const unsigned short* WbP = (const unsigned short*)Wsrc;   // FAST: bf16 [D][VPAD]
    const float*          WfP = (const float*)Wsrc;            // !FAST: fp32 [D][V]
    const int wrow = w32 + (lane >> 2);
    const unsigned short* wSrc = WbP + (size_t)wrow * VPAD + (lane & 3) * 8;

    auto stageA = [&](int buf, int ks) {   // 4 x gload_lds, 1 KB each (8 rows x 128 B)
#pragma unroll
        for (int j = 0; j < 4; ++j)
            gload_lds16(aSrc + ks + (size_t)j * 8 * V,
                        smem + buf * 16384 + w32 * 128 + j * 1024);
    };
    auto stageW = [&](int buf, int ks) {
        if (FAST) {                        // 2 x gload_lds, 1 KB each (16 rows x 64 B)
#pragma unroll
            for (int j = 0; j < 2; ++j)
                gload_lds16(wSrc + ks + (size_t)j * 16 * VPAD,
                            smem + 32768 + buf * 8192 + w32 * 64 + j * 1024);
        } else {                           // guarded reg-staged from fp32
#pragma unroll
            for (int j = 0; j < 2; ++j) {
                const int slot = tid + j * 256;      // 512 slots x 16 B
                const int d    = slot >> 2;
                const int cp   = slot & 3;
                const int kg   = ks + cp * 8;
                uint4v u = {0u, 0u, 0u, 0u};
                if (kg + 8 <= V) {
                    const f32x4* sp = reinterpret_cast<const f32x4*>(WfP + (size_t)d * V + kg);
                    f32x4 v0 = sp[0], v1 = sp[1];
                    u.x = pk2(v0[0], v0[1]); u.y = pk2(v0[2], v0[3]);
                    u.z = pk2(v1[0], v1[1]); u.w = pk2(v1[2], v1[3]);
                }
                *reinterpret_cast<uint4v*>(smem + 32768 + buf * 8192 + d * 64 + cp * 16) = u;
            }
        }
    };
    auto stageAtail = [&](int buf, int ks) {  // guarded, 4-float granular, zero OOB
#pragma unroll
        for (int j = 0; j < 4; ++j) {
            const int slot = tid + j * 256;       // 1024 slots x 16 B
            const int row  = slot >> 3;
            const int cp   = slot & 7;
            const int cd   = cp ^ (row & 7);
            const int kg   = ks + cd * 4;
            f32x4 v = {0.f, 0.f, 0.f, 0.f};
            if (kg + 4 <= V)
                v = *reinterpret_cast<const f32x4*>(Ain + (size_t)(m0 + row) * V + kg);
            *reinterpret_cast<f32x4*>(smem + buf * 16384 + row * 128 + cp * 16) = v;
        }
    };

    int cur = 0;
    if (nfull > 0) stageA(0, k0); else stageAtail(0, k0);
    stageW(0, k0);
    __syncthreads();

    for (int t = 0; t < nsteps; ++t) {
        const int tn = t + 1;
        if (tn < nsteps) {                 // stage next step into the other buffer
            const int ksn = k0 + tn * 32;
            if (tn < nfull) stageA(cur ^ 1, ksn); else stageAtail(cur ^ 1, ksn);
            stageW(cur ^ 1, ksn);
        }
        // ---- compute step t from buf[cur] ----
        const char* Ab = smem + cur * 16384;
        const char* Wl = smem + 32768 + cur * 8192;
        bf16x8 af[2];
        const int c0 = (2 * kg4) ^ (fr & 7);
#pragma unroll
        for (int m = 0; m < 2; ++m) {
            const char* rb = Ab + (w32 + m * 16 + fr) * 128;
            f32x4 lo = *reinterpret_cast<const f32x4*>(rb + c0 * 16);
            f32x4 hi = *reinterpret_cast<const f32x4*>(rb + (c0 ^ 1) * 16);
            af[m] = pack8(lo, hi);
        }
#pragma unroll
        for (int n = 0; n < 8; ++n) {
            const bf16x8 wf = *reinterpret_cast<const bf16x8*>(Wl + (n * 16 + fr) * 64 + kg4 * 16);
            acc[0][n] = __builtin_amdgcn_mfma_f32_16x16x32_bf16(af[0], wf, acc[0][n], 0, 0, 0);
            acc[1][n] = __builtin_amdgcn_mfma_f32_16x16x32_bf16(af[1], wf, acc[1][n], 0, 0, 0);
        }
        __syncthreads();
        cur ^= 1;
    }

    // ---- epilogue (C/D layout: col = lane&15, row = kg4*4 + jj) ----
    if (!FAST) {
        float* outp = (float*)part;        // fp32 [B][D], atomic accumulate
#pragma unroll
        for (int m = 0; m < 2; ++m) {
            const int r0 = m0 + w32 + m * 16 + kg4 * 4;
#pragma unroll
            for (int n = 0; n < 8; ++n) {
                const int c = n * 16 + fr;
#pragma unroll
                for (int jj = 0; jj < 4; ++jj)
                    atomicAdd(&outp[(size_t)(r0 + jj) * D + c], acc[m][n][jj]);
            }
        }
        return;
    }
    unsigned short* Cs = (unsigned short*)smem;   // [128][128] bf16 = 32 KB
#pragma unroll
    for (int m = 0; m < 2; ++m) {
        const int r0 = w32 + m * 16 + kg4 * 4;
#pragma unroll
        for (int n = 0; n < 8; ++n) {
            const int c = n * 16 + fr;
#pragma unroll
            for (int jj = 0; jj < 4; ++jj)
                Cs[(r0 + jj) * 128 + c] = f2bf(acc[m][n][jj]);
        }
    }
    __syncthreads();
    char* dstb = (char*)part + ((size_t)s * B + m0) * (D * 2);   // [s][b][d] bf16
#pragma unroll
    for (int it = 0; it < 8; ++it) {
        const int off = (it * 256 + tid) * 16;                   // 32 KB coalesced
        uint4v v = *reinterpret_cast<const uint4v*>(smem + off);
        *reinterpret_cast<uint4v*>(dstb + off) = v;
    }
}

// ---------------- stage 2: reduce splits + gathered cls dots + BCE + mean ----------------
__global__ __launch_bounds__(256)
void w2v_loss(const void* __restrict__ part, int part_bf16,
              const float* __restrict__ Wcls, const int* __restrict__ pathIdx,
              const float* __restrict__ codes, const float* __restrict__ mask,
              float* __restrict__ out) {
    const int lane = threadIdx.x & 63;
    const int wid  = threadIdx.x >> 6;
    const int b    = blockIdx.x * 4 + wid;     // one wave per sample

    float x0 = 0.f, x1 = 0.f;                  // x[b][2*lane], x[b][2*lane+1]
    if (part_bf16) {
        const unsigned* pb = (const unsigned*)part;   // 64 u32 per [s][b] row
#pragma unroll 8
        for (int s = 0; s < NSPLIT; ++s) {
            unsigned u = pb[((size_t)s * B + b) * 64 + lane];
            x0 += __uint_as_float(u << 16);
            x1 += __uint_as_float(u & 0xFFFF0000u);
        }
    } else {
        const float* pf = (const float*)part;         // [B][D] fp32, pre-reduced
        const float2 v = *reinterpret_cast<const float2*>(&pf[(size_t)b * D + lane * 2]);
        x0 = v.x; x1 = v.y;
    }

    float lsum = 0.f, msum = 0.f;
#pragma unroll
    for (int p = 0; p < P; ++p) {
        int node = pathIdx[b * P + p];
        const float2 w = *reinterpret_cast<const float2*>(&Wcls[(size_t)node * D + lane * 2]);
        float d = x0 * w.x + x1 * w.y;
#pragma unroll
        for (int off = 1; off < 64; off <<= 1)
            d += __shfl_xor(d, off, 64);
        float t  = codes[b * P + p];
        float mm = mask[b * P + p];
        float loss = fmaxf(d, 0.f) - d * t + log1pf(__expf(-fabsf(d)));
        lsum += loss * mm;
        msum += mm;
    }
    float per = (msum > 0.f) ? (lsum / msum) : 0.f;

    __shared__ float wsum[4];
    if (lane == 0) wsum[wid] = per;
    __syncthreads();
    if (threadIdx.x == 0) {
        float ssum = wsum[0] + wsum[1] + wsum[2] + wsum[3];
        atomicAdd(out, ssum * (1.0f / (float)B));
    }
}

extern "C" void kernel_launch(void* const* d_in, const int* in_sizes, int n_in,
                              void* d_out, int out_size, void* d_ws, size_t ws_size,
                              hipStream_t stream) {
    const float* inputs = (const float*)d_in[0];   // [B,V]
    const float* W_emb  = (const float*)d_in[1];   // [D,V]
    const float* W_cls  = (const float*)d_in[2];   // [V,D]
    const int*   path   = (const int*)  d_in[3];   // [B,P]
    const float* codes  = (const float*)d_in[4];   // [B,P]
    const float* mask   = (const float*)d_in[5];   // [B,P]
    float* out = (float*)d_out;

    hipMemsetAsync(d_out, 0, sizeof(float), stream);

    const size_t wb_bytes  = (size_t)D * VPAD * 2;                    // ~13.0 MB
    const size_t part_off  = (wb_bytes + 255) & ~(size_t)255;
    const size_t part_need = part_off + (size_t)NSPLIT * B * D * 2;   // ~38.2 MB

    if (ws_size >= part_need) {
        unsigned short* Wb = (unsigned short*)d_ws;
        char* partp = (char*)d_ws + part_off;
        w2v_wcast<<<dim3((unsigned)((size_t)D * VPAD / 8 / 256)), dim3(256), 0, stream>>>(W_emb, Wb);
        w2v_gemm<1><<<dim3(NMT * NSPLIT), dim3(256), 0, stream>>>(inputs, Wb, partp);
        w2v_loss<<<dim3(B / 4), dim3(256), 0, stream>>>(partp, 1, W_cls, path, codes, mask, out);
    } else {
        hipMemsetAsync(d_ws, 0, (size_t)B * D * sizeof(float), stream);
        w2v_gemm<0><<<dim3(NMT * NSPLIT), dim3(256), 0, stream>>>(inputs, W_emb, d_ws);
        w2v_loss<<<dim3(B / 4), dim3(256), 0, stream>>>(d_ws, 0, W_cls, path, codes, mask, out);
    }
}